// Round 1
// baseline (224.331 us; speedup 1.0000x reference)
//
#include <hip/hip_runtime.h>
#include <math.h>

#define WIDTH 960
#define NTOT (16 * 544 * 960)

__device__ __forceinline__ float smooth_l1f(float d) {
    float ad = fabsf(d);
    return ad < 1.0f ? 0.5f * d * d : ad - 0.5f;
}

__global__ __launch_bounds__(256) void loss_kernel(
    const float* __restrict__ dl,
    const float* __restrict__ seg_r,
    const float* __restrict__ dlgt,
    const float* __restrict__ lgt,
    double* __restrict__ ws)
{
    const int n4 = NTOT / 4;
    float cnt = 0.0f, s_loss = 0.0f, s_recon = 0.0f;

    for (int i4 = blockIdx.x * blockDim.x + threadIdx.x; i4 < n4;
         i4 += gridDim.x * blockDim.x) {
        int i  = i4 << 2;
        int w0 = i % WIDTH;                 // W % 4 == 0: all 4 elems same row
        const float* __restrict__ row = seg_r + (i - w0);

        float4 d4 = ((const float4*)dl)[i4];
        float4 g4 = ((const float4*)lgt)[i4];
        float4 t4 = ((const float4*)dlgt)[i4];
        float dv[4] = {d4.x, d4.y, d4.z, d4.w};
        float gv[4] = {g4.x, g4.y, g4.z, g4.w};
        float tv[4] = {t4.x, t4.y, t4.z, t4.w};

        #pragma unroll
        for (int k = 0; k < 4; ++k) {
            float lg = gv[k];
            if (lg > 0.0f) {
                cnt += 1.0f;
                float d = dv[k];
                s_loss += smooth_l1f(d - tv[k]);

                // horizontal bilinear warp with zeros padding
                float sx  = (float)(w0 + k) - d;
                float x0f = floorf(sx);
                float wx  = sx - x0f;
                int x0i = (int)x0f;
                int x1i = x0i + 1;
                float g0 = (x0i >= 0 && x0i < WIDTH) ? row[x0i] : 0.0f;
                float g1 = (x1i >= 0 && x1i < WIDTH) ? row[x1i] : 0.0f;
                float wv = (1.0f - wx) * g0 + wx * g1;
                float recon = 1.0f / (1.0f + __expf(-wv));
                s_recon += smooth_l1f(recon - lg);
            }
        }
    }

    // wave(64) shuffle reduction in double
    double dc = (double)cnt, dlo = (double)s_loss, dre = (double)s_recon;
    for (int off = 32; off > 0; off >>= 1) {
        dc  += __shfl_down(dc,  off, 64);
        dlo += __shfl_down(dlo, off, 64);
        dre += __shfl_down(dre, off, 64);
    }

    __shared__ double sh[3][4];
    int lane = threadIdx.x & 63;
    int wid  = threadIdx.x >> 6;
    if (lane == 0) { sh[0][wid] = dc; sh[1][wid] = dlo; sh[2][wid] = dre; }
    __syncthreads();
    if (threadIdx.x == 0) {
        double c = 0, l = 0, r = 0;
        #pragma unroll
        for (int j = 0; j < 4; ++j) { c += sh[0][j]; l += sh[1][j]; r += sh[2][j]; }
        atomicAdd(&ws[0], c);
        atomicAdd(&ws[1], l);
        atomicAdd(&ws[2], r);
    }
}

__global__ void finalize_kernel(const double* __restrict__ ws, float* __restrict__ out)
{
    double cnt = ws[0];
    double l   = ws[1] / cnt;
    if (isnan(l)) l = 0.0;
    double lr  = ws[2] / cnt;
    out[0] = (float)(l + 0.5 * lr);
}

extern "C" void kernel_launch(void* const* d_in, const int* in_sizes, int n_in,
                              void* d_out, int out_size, void* d_ws, size_t ws_size,
                              hipStream_t stream) {
    const float* dl    = (const float*)d_in[0];
    const float* seg_r = (const float*)d_in[1];
    const float* dlgt  = (const float*)d_in[2];
    const float* lgt   = (const float*)d_in[3];
    double* ws = (double*)d_ws;

    // d_ws is poisoned to 0xAA before every call — zero the accumulators.
    hipMemsetAsync(d_ws, 0, 3 * sizeof(double), stream);

    // n4 = 2,088,960 = 2040 blocks * 256 threads * 4 iters exactly
    loss_kernel<<<2040, 256, 0, stream>>>(dl, seg_r, dlgt, lgt, ws);
    finalize_kernel<<<1, 1, 0, stream>>>(ws, (float*)d_out);
}

// Round 2
// 156.853 us; speedup vs baseline: 1.4302x; 1.4302x over previous
//
#include <hip/hip_runtime.h>
#include <math.h>

#define W 960
#define W4 240
#define NROWS (16 * 544)            // 8704 flat (b,h) rows
#define ROWS_PB 4
#define NBLOCKS (NROWS / ROWS_PB)   // 2176
#define LDS_STRIDE 964              // pad +4 floats, keeps float4 alignment

__device__ __forceinline__ float smooth_l1f(float d) {
    float ad = fabsf(d);
    return ad < 1.0f ? 0.5f * d * d : ad - 0.5f;
}

__global__ __launch_bounds__(256) void loss_kernel(
    const float* __restrict__ dl,
    const float* __restrict__ seg_r,
    const float* __restrict__ dlgt,
    const float* __restrict__ lgt,
    double* __restrict__ ws)
{
    __shared__ float srow[ROWS_PB * LDS_STRIDE];
    const int tid   = threadIdx.x;
    const int base4 = blockIdx.x * (ROWS_PB * W4);   // float4 index of block's first elem

    // ---- stage seg_r rows into LDS (coalesced float4) ----
    for (int t = tid; t < ROWS_PB * W4; t += 256) {
        float4 v = ((const float4*)seg_r)[base4 + t];
        int r = t / W4;
        int c = t - r * W4;
        float* dst = &srow[r * LDS_STRIDE + (c << 2)];
        dst[0] = v.x; dst[1] = v.y; dst[2] = v.z; dst[3] = v.w;
    }
    __syncthreads();

    // ---- branchless fused loss, gathers from LDS ----
    float cnt = 0.f, s_loss = 0.f, s_recon = 0.f;
    for (int t = tid; t < ROWS_PB * W4; t += 256) {
        int r  = t / W4;
        int c4 = t - r * W4;
        int g4 = base4 + t;
        float4 d4 = ((const float4*)dl)[g4];
        float4 l4 = ((const float4*)lgt)[g4];
        float4 t4 = ((const float4*)dlgt)[g4];
        const float* __restrict__ lrow = &srow[r * LDS_STRIDE];

        float dv[4] = {d4.x, d4.y, d4.z, d4.w};
        float lv[4] = {l4.x, l4.y, l4.z, l4.w};
        float tv[4] = {t4.x, t4.y, t4.z, t4.w};

        #pragma unroll
        for (int k = 0; k < 4; ++k) {
            float m = lv[k] > 0.f ? 1.f : 0.f;
            cnt += m;
            float d = dv[k];
            s_loss += m * smooth_l1f(d - tv[k]);

            float sx  = (float)((c4 << 2) + k) - d;
            float x0f = floorf(sx);
            float wx  = sx - x0f;
            int x0 = (int)x0f;
            int x1 = x0 + 1;
            float m0 = (x0 >= 0 && x0 < W) ? 1.f : 0.f;
            float m1 = (x1 >= 0 && x1 < W) ? 1.f : 0.f;
            int x0c = min(max(x0, 0), W - 1);
            int x1c = min(max(x1, 0), W - 1);
            float g0 = lrow[x0c] * m0;
            float g1 = lrow[x1c] * m1;
            float wv = (1.f - wx) * g0 + wx * g1;
            float recon = 1.f / (1.f + __expf(-wv));
            s_recon += m * smooth_l1f(recon - lv[k]);
        }
    }

    // ---- block reduction (wave shuffle in double, LDS across 4 waves) ----
    double dc = (double)cnt, dlo = (double)s_loss, dre = (double)s_recon;
    for (int off = 32; off > 0; off >>= 1) {
        dc  += __shfl_down(dc,  off, 64);
        dlo += __shfl_down(dlo, off, 64);
        dre += __shfl_down(dre, off, 64);
    }
    __shared__ double sh[3][4];
    int lane = tid & 63, wid = tid >> 6;
    if (lane == 0) { sh[0][wid] = dc; sh[1][wid] = dlo; sh[2][wid] = dre; }
    __syncthreads();
    if (tid == 0) {
        double c = 0, l = 0, r = 0;
        #pragma unroll
        for (int j = 0; j < 4; ++j) { c += sh[0][j]; l += sh[1][j]; r += sh[2][j]; }
        ws[blockIdx.x]               = c;
        ws[NBLOCKS + blockIdx.x]     = l;
        ws[2 * NBLOCKS + blockIdx.x] = r;
    }
}

__global__ __launch_bounds__(256) void finalize_kernel(
    const double* __restrict__ ws, float* __restrict__ out)
{
    double c = 0, l = 0, r = 0;
    for (int i = threadIdx.x; i < NBLOCKS; i += 256) {
        c += ws[i];
        l += ws[NBLOCKS + i];
        r += ws[2 * NBLOCKS + i];
    }
    for (int off = 32; off > 0; off >>= 1) {
        c += __shfl_down(c, off, 64);
        l += __shfl_down(l, off, 64);
        r += __shfl_down(r, off, 64);
    }
    __shared__ double sh[3][4];
    int lane = threadIdx.x & 63, wid = threadIdx.x >> 6;
    if (lane == 0) { sh[0][wid] = c; sh[1][wid] = l; sh[2][wid] = r; }
    __syncthreads();
    if (threadIdx.x == 0) {
        double cc = 0, ll = 0, rr = 0;
        #pragma unroll
        for (int j = 0; j < 4; ++j) { cc += sh[0][j]; ll += sh[1][j]; rr += sh[2][j]; }
        double loss = ll / cc;
        if (isnan(loss)) loss = 0.0;
        out[0] = (float)(loss + 0.5 * (rr / cc));
    }
}

extern "C" void kernel_launch(void* const* d_in, const int* in_sizes, int n_in,
                              void* d_out, int out_size, void* d_ws, size_t ws_size,
                              hipStream_t stream) {
    const float* dl    = (const float*)d_in[0];
    const float* seg_r = (const float*)d_in[1];
    const float* dlgt  = (const float*)d_in[2];
    const float* lgt   = (const float*)d_in[3];
    double* ws = (double*)d_ws;   // 3 * NBLOCKS doubles; every slot written each call

    loss_kernel<<<NBLOCKS, 256, 0, stream>>>(dl, seg_r, dlgt, lgt, ws);
    finalize_kernel<<<1, 256, 0, stream>>>(ws, (float*)d_out);
}